// Round 12
// baseline (202.656 us; speedup 1.0000x reference)
//
#include <hip/hip_runtime.h>
#include <float.h>

// Problem constants
#define B_   8
#define T_   2048
#define CIN  1024      // INPUT_DIM
#define DD   8         // CODEBOOK_DIM
#define KC   8192      // CODEBOOK_SIZE
#define NTOK (B_*T_)   // 16384 tokens
#define NSLICE 32
#define SLICE (KC/NSLICE)   // 256 codes per slice

// d_out layout, ALL float32: out[B,CIN,T] | indices[B,T] (as float values) | z_e[B,DD,T]
#define IDX_OFF ((size_t)B_*CIN*T_)       // 16777216
#define ZE_OFF  (IDX_OFF + NTOK)          // 16793600

// ws layout (float units), ~4.9 MiB total
#define WS_WT    0                         // 8192  : W_in^T [c][d]
#define WS_CBN   (WS_WT + CIN*DD)          // 65536 : normalized codebook [j][d]
#define WS_SC    (WS_CBN + KC*DD)          // 8192  : sum(cn^2)
#define WS_ENCN  (WS_SC + KC)              // 131072: normalized enc [t][d]
#define WS_SE    (WS_ENCN + NTOK*DD)       // 16384 : sum(en^2)
#define WS_PDIST (WS_SE + NTOK)            // 524288: best dist [32][16384]
#define WS_PIDX  (WS_PDIST + NSLICE*NTOK)  // 524288: best idx  [32][16384]

// ---------------- Kernel 0: prep — normalize codebook + transpose W_in ----------------
// grid = 64 blocks x 256 (16384 threads: 8192 codebook rows + 8192 W_in elements)
__global__ __launch_bounds__(256) void prep(const float* __restrict__ cb,
                                            const float* __restrict__ W_in,
                                            float* __restrict__ ws) {
    int gt = blockIdx.x * 256 + threadIdx.x;
    if (gt < KC) {
        const float4* src = (const float4*)(cb + (size_t)gt * DD);
        float4 a = src[0], bv = src[1];
        float c[8] = {a.x, a.y, a.z, a.w, bv.x, bv.y, bv.z, bv.w};
        // normalize chain: bitwise identical to the round-7/10 staging chain
        float s2 = __fmul_rn(c[0], c[0]);
        #pragma unroll
        for (int k = 1; k < 8; ++k) s2 = __fadd_rn(s2, __fmul_rn(c[k], c[k]));
        float m = fmaxf(sqrtf(s2), 1e-12f);
        float cn[8];
        #pragma unroll
        for (int k = 0; k < 8; ++k) cn[k] = c[k] / m;
        float sc = __fmul_rn(cn[0], cn[0]);
        #pragma unroll
        for (int k = 1; k < 8; ++k) sc = __fadd_rn(sc, __fmul_rn(cn[k], cn[k]));
        float4* dst = (float4*)(ws + WS_CBN + (size_t)gt * DD);
        dst[0] = make_float4(cn[0], cn[1], cn[2], cn[3]);
        dst[1] = make_float4(cn[4], cn[5], cn[6], cn[7]);
        ws[WS_SC + gt] = sc;
    } else if (gt < KC + CIN * DD) {
        int i = gt - KC;               // 0..8191
        int c = i >> 3, d = i & 7;
        ws[WS_WT + i] = W_in[d * CIN + c];
    }
}

// ---------------- Kernel 1: in-projection + normalize enc ----------------
// grid = 256 blocks (64 tokens each); block = 512 = 8 waves, wave g = c-group, lane = token
// Per-token arithmetic chain is VERBATIM round-7 (8x128-channel fmaf chains, pairwise
// tree merge, sequential-rounded normalize). Do not reassociate — argmin bits depend on it.
__global__ __launch_bounds__(512) void inproj(const float* __restrict__ z,
                                              const float* __restrict__ b_in,
                                              float* __restrict__ out,
                                              float* __restrict__ ws) {
    __shared__ float red[8][64][9];    // +1 pad word per token row (9 coprime 32 banks), 18 KiB
    int tid = threadIdx.x;
    int g = __builtin_amdgcn_readfirstlane(tid >> 6);   // wave-uniform c-group
    int tl = tid & 63;                                   // token lane

    int bid = blockIdx.x;
    int b = bid >> 5, tg = bid & 31;
    int t0 = tg * 64;

    const float* zp = z + ((size_t)b * CIN) * T_ + (t0 + tl);
    const float* wt = ws + WS_WT;
    float acc[8] = {0, 0, 0, 0, 0, 0, 0, 0};
    int cbeg = g * 128;
    #pragma unroll 8
    for (int i = 0; i < 128; ++i) {
        int c = cbeg + i;
        float v = zp[(size_t)c * T_];          // 256 B/wave coalesced
        const float* w = wt + c * 8;           // wave-uniform -> s_load_dwordx8
        acc[0] = fmaf(w[0], v, acc[0]);
        acc[1] = fmaf(w[1], v, acc[1]);
        acc[2] = fmaf(w[2], v, acc[2]);
        acc[3] = fmaf(w[3], v, acc[3]);
        acc[4] = fmaf(w[4], v, acc[4]);
        acc[5] = fmaf(w[5], v, acc[5]);
        acc[6] = fmaf(w[6], v, acc[6]);
        acc[7] = fmaf(w[7], v, acc[7]);
    }
    #pragma unroll
    for (int d = 0; d < 8; ++d) red[g][tl][d] = acc[d];
    __syncthreads();

    if (tid < 64) {
        int tt = tid;
        float ze[8];
        #pragma unroll
        for (int d = 0; d < 8; ++d) {
            float s01 = (red[0][tt][d] + red[1][tt][d]) + (red[2][tt][d] + red[3][tt][d]);
            float s23 = (red[4][tt][d] + red[5][tt][d]) + (red[6][tt][d] + red[7][tt][d]);
            ze[d] = (s01 + s23) + b_in[d];
        }
        float* zeo = out + ZE_OFF + ((size_t)b * DD) * T_ + (t0 + tt);
        #pragma unroll
        for (int d = 0; d < 8; ++d) zeo[(size_t)d * T_] = ze[d];
        // normalize: squares rounded individually, sequential adds (verbatim)
        float s2 = __fmul_rn(ze[0], ze[0]);
        #pragma unroll
        for (int d = 1; d < 8; ++d) s2 = __fadd_rn(s2, __fmul_rn(ze[d], ze[d]));
        float m = fmaxf(sqrtf(s2), 1e-12f);
        float en[8];
        #pragma unroll
        for (int d = 0; d < 8; ++d) en[d] = ze[d] / m;
        float se = __fmul_rn(en[0], en[0]);
        #pragma unroll
        for (int d = 1; d < 8; ++d) se = __fadd_rn(se, __fmul_rn(en[d], en[d]));
        int token = b * T_ + t0 + tt;
        float4* ep = (float4*)(ws + WS_ENCN + (size_t)token * DD);
        ep[0] = make_float4(en[0], en[1], en[2], en[3]);
        ep[1] = make_float4(en[4], en[5], en[6], en[7]);
        ws[WS_SE + token] = se;
    }
}

// ---------------- Kernel 2: codebook search, 2 tokens/thread, no LDS ----------------
// grid = 1024 = 32 token-groups(512 tok) x 32 slices; block = 256 (4 blocks/CU, 16 waves/CU)
__global__ __launch_bounds__(256) void vq_search(float* __restrict__ ws) {
    int tid = threadIdx.x;
    int bid = blockIdx.x;
    int sl = bid & (NSLICE - 1);
    int tg = bid >> 5;

    int token0 = tg * 512 + tid * 2;
    float e[2][8], se[2];
    #pragma unroll
    for (int m = 0; m < 2; ++m) {
        const float4* ep = (const float4*)(ws + WS_ENCN + (size_t)(token0 + m) * DD);
        float4 a = ep[0], bv = ep[1];
        e[m][0] = a.x;  e[m][1] = a.y;  e[m][2] = a.z;  e[m][3] = a.w;
        e[m][4] = bv.x; e[m][5] = bv.y; e[m][6] = bv.z; e[m][7] = bv.w;
        se[m] = ws[WS_SE + token0 + m];
    }

    const float* cbn = ws + WS_CBN + (size_t)sl * SLICE * DD;  // uniform base
    const float* csc = ws + WS_SC + sl * SLICE;

    float best[2] = {FLT_MAX, FLT_MAX};
    int bi[2] = {0, 0};
    // dist = (se - 2*dot) + sc; chain + strict-< ascending tie order = round-7 bits
    #pragma unroll 4
    for (int j = 0; j < SLICE; ++j) {
        const float* cd = cbn + j * 8;        // wave-uniform -> s_load_dwordx8
        float sc = csc[j];
        #pragma unroll
        for (int m = 0; m < 2; ++m) {
            float dot = e[m][0] * cd[0];
            #pragma unroll
            for (int k = 1; k < 8; ++k) dot = fmaf(e[m][k], cd[k], dot);
            float dist = __fadd_rn(fmaf(-2.f, dot, se[m]), sc);
            bool p = dist < best[m];
            best[m] = p ? dist : best[m];
            bi[m]   = p ? j : bi[m];
        }
    }
    *(float2*)(ws + WS_PDIST + (size_t)sl * NTOK + token0) = make_float2(best[0], best[1]);
    *(int2*)((int*)ws + WS_PIDX + (size_t)sl * NTOK + token0) =
        make_int2(sl * SLICE + bi[0], sl * SLICE + bi[1]);
}

// ---------------- Kernel 3: merge + indices + gather + STE + out-projection ----------------
// grid = 256 blocks (64 tokens each); block = 512 = 8 waves, wave = 128-channel group
__global__ __launch_bounds__(512) void outproj(const float* __restrict__ ws,
                                               const float* __restrict__ cb,
                                               const float* __restrict__ W_out,
                                               const float* __restrict__ b_out,
                                               float* __restrict__ out) {
    __shared__ float zql[DD * 64];   // [d][t], 2 KiB
    int tid = threadIdx.x;
    int g = __builtin_amdgcn_readfirstlane(tid >> 6);   // wave-uniform c-group
    int tl = tid & 63;                                   // token lane

    int bid = blockIdx.x;
    int b = bid >> 5, tg = bid & 31;
    int t0 = tg * 64;

    if (tid < 64) {
        int token = b * T_ + t0 + tl;
        // merge 32 slice minima (strict <: earlier slice wins ties)
        float bestv = ws[WS_PDIST + token];
        int bi = ((const int*)ws)[WS_PIDX + token];
        #pragma unroll
        for (int s = 1; s < NSLICE; ++s) {
            float d = ws[WS_PDIST + (size_t)s * NTOK + token];
            int i2  = ((const int*)ws)[WS_PIDX + (size_t)s * NTOK + token];
            bool p = d < bestv;
            bestv = p ? d : bestv;
            bi    = p ? i2 : bi;
        }
        out[IDX_OFF + token] = (float)bi;   // index as float value
        // STE: z_q_out = z_e + (z_q - z_e), elementwise fp32 (verbatim chain)
        const float* zep = out + ZE_OFF + ((size_t)b * DD) * T_ + (t0 + tl);
        float4 ca = *(const float4*)(cb + (size_t)bi * DD);
        float4 cb2 = *(const float4*)(cb + (size_t)bi * DD + 4);
        float cv[8] = {ca.x, ca.y, ca.z, ca.w, cb2.x, cb2.y, cb2.z, cb2.w};
        #pragma unroll
        for (int d = 0; d < 8; ++d) {
            float ze = zep[(size_t)d * T_];
            zql[d * 64 + tl] = __fadd_rn(ze, __fsub_rn(cv[d], ze));
        }
    }
    __syncthreads();

    float q[8];
    #pragma unroll
    for (int k = 0; k < 8; ++k) q[k] = zql[k * 64 + tl];   // stride-1 lanes, conflict-free

    float* op = out + ((size_t)b * CIN) * T_ + t0 + tl;
    int cbeg = g * 128;
    #pragma unroll 8
    for (int i = 0; i < 128; ++i) {
        int c = cbeg + i;
        const float* w = W_out + (size_t)c * 8;   // wave-uniform -> s_load_dwordx8
        float bc = b_out[c];                       // wave-uniform -> s_load
        float dot = q[0] * w[0];
        dot = fmaf(q[1], w[1], dot);
        dot = fmaf(q[2], w[2], dot);
        dot = fmaf(q[3], w[3], dot);
        dot = fmaf(q[4], w[4], dot);
        dot = fmaf(q[5], w[5], dot);
        dot = fmaf(q[6], w[6], dot);
        dot = fmaf(q[7], w[7], dot);
        op[(size_t)c * T_] = dot + bc;             // 256 B/wave coalesced
    }
}

extern "C" void kernel_launch(void* const* d_in, const int* in_sizes, int n_in,
                              void* d_out, int out_size, void* d_ws, size_t ws_size,
                              hipStream_t stream) {
    const float* z     = (const float*)d_in[0];
    const float* W_in  = (const float*)d_in[1];
    const float* b_in  = (const float*)d_in[2];
    const float* W_out = (const float*)d_in[3];
    const float* b_out = (const float*)d_in[4];
    const float* cb    = (const float*)d_in[5];
    float* out = (float*)d_out;
    float* ws  = (float*)d_ws;

    prep<<<64, 256, 0, stream>>>(cb, W_in, ws);
    inproj<<<NTOK / 64, 512, 0, stream>>>(z, b_in, out, ws);
    vq_search<<<(NTOK / 512) * NSLICE, 256, 0, stream>>>(ws);
    outproj<<<NTOK / 64, 512, 0, stream>>>(ws, cb, W_out, b_out, out);
}